// Round 6
// baseline (124.864 us; speedup 1.0000x reference)
//
#include <hip/hip_runtime.h>
#include <cstddef>

// Problem constants
#define BB 8
#define CC 64
#define OO 64
#define HH 256
#define WW 256
#define MODES 16

// Workspace layout (float offsets)
//  [0)       pft [B*C][4][2][16][2]  131072   (per-stripe partial spectra)
//  [131072)  g   [2][B][O][256]      262144
#define WS_PFT 0
#define WS_G   131072

#define TWO_PI 6.2831853071795864769f

typedef __attribute__((ext_vector_type(8)))  short short8v;
typedef __attribute__((ext_vector_type(4)))  int   int4v;
typedef __attribute__((ext_vector_type(16))) float f32x16;

// HW packed f32->bf16 (RNE): lo = bf16(a), hi = bf16(b)
__device__ __forceinline__ unsigned pack_bf16(float a, float b) {
    unsigned r;
    asm("v_cvt_pk_bf16_f32 %0, %1, %2" : "=v"(r) : "v"(a), "v"(b));
    return r;
}

// ---------------------------------------------------------------------------
// K1: grid = B*C*4. Block j of slice bc handles rows [j*64, j*64+64).
// One pass over its stripe produces BOTH 16-mode partial spectra directly
// (DFT is linear, so per-stripe partials sum to the full transform):
//   prow[k] = sum_{r<64} rowmean(h0+r) * e^{-i*2pi*k*(h0+r)/256}
//   pcol[k] = sum_{w}    colpartial(w) * e^{-i*2pi*k*w/256}
// -> pft[bc][j][0][k] = prow, pft[bc][j][1][k] = pcol (raw, norms later).
__global__ void k_means_dft(const float* __restrict__ x,
                            float* __restrict__ pft) { // [512][4][2][16][2]
    const int blk = blockIdx.x;                  // bc*4 + j
    const int bc  = blk >> 2;
    const int j   = blk & 3;
    const int t   = threadIdx.x;
    const int wave = t >> 6;
    const int lane = t & 63;
    const float* xs = x + (size_t)bc * (HH * WW);

    __shared__ float colsum[4][WW];
    __shared__ float cs[WW];
    __shared__ float rm[64];

    float c0 = 0.f, c1 = 0.f, c2 = 0.f, c3 = 0.f;
    const int h0 = j * 64 + wave * 16;
    for (int r = 0; r < 16; ++r) {
        const int h = h0 + r;
        const float4 v = *reinterpret_cast<const float4*>(xs + (size_t)h * WW + lane * 4);
        c0 += v.x; c1 += v.y; c2 += v.z; c3 += v.w;
        float rs = (v.x + v.y) + (v.z + v.w);
        #pragma unroll
        for (int off = 32; off > 0; off >>= 1) rs += __shfl_xor(rs, off, 64);
        if (lane == 0) rm[wave * 16 + r] = rs * (1.0f / WW);   // row mean
    }
    colsum[wave][lane * 4 + 0] = c0;
    colsum[wave][lane * 4 + 1] = c1;
    colsum[wave][lane * 4 + 2] = c2;
    colsum[wave][lane * 4 + 3] = c3;
    __syncthreads();
    cs[t] = (colsum[0][t] + colsum[1][t]) + (colsum[2][t] + colsum[3][t]);
    __syncthreads();

    // 16-mode partial DFTs. thread t: mode k = t>>4, sub-chunk = t&15.
    const int k   = t >> 4;
    const int sub = t & 15;
    const float wk = TWO_PI * (float)k / 256.0f;

    // column-branch: full 256-point DFT of this stripe's column partial sums
    float cre = 0.f, cim = 0.f;
    #pragma unroll
    for (int i = 0; i < 16; ++i) {
        const int w = sub * 16 + i;
        float s, c;
        sincosf(wk * (float)w, &s, &c);
        cre += cs[w] * c;
        cim -= cs[w] * s;
    }
    // row-branch: 64-point partial DFT of this stripe's row means (global h!)
    float rre = 0.f, rim = 0.f;
    #pragma unroll
    for (int i = 0; i < 4; ++i) {
        const int r = sub * 4 + i;
        float s, c;
        sincosf(wk * (float)(j * 64 + r), &s, &c);
        rre += rm[r] * c;
        rim -= rm[r] * s;
    }
    #pragma unroll
    for (int m = 1; m < 16; m <<= 1) {
        cre += __shfl_xor(cre, m, 64);
        cim += __shfl_xor(cim, m, 64);
        rre += __shfl_xor(rre, m, 64);
        rim += __shfl_xor(rim, m, 64);
    }
    if (sub == 0) {
        float* p = pft + (((size_t)blk * 2 + 0) * 16 + k) * 2;
        p[0] = rre; p[1] = rim;
        p += 32;                         // br=1 slot
        p[0] = cre; p[1] = cim;
    }
}

// ---------------------------------------------------------------------------
// K2: grid = 16 (br*8+b). Reduce stripe partials -> ft, channel-mix in mode
// space, build twiddle table, synthesize g[br,b,o,0..255]. mix_b folded into
// the br==0 (gx) output.
__global__ void k_spectral(const float* __restrict__ pft,
                           const float* __restrict__ wxr, const float* __restrict__ wxi,
                           const float* __restrict__ wyr, const float* __restrict__ wyi,
                           const float* __restrict__ mb,
                           float* __restrict__ g) {
    const int blk = blockIdx.x;      // br*8 + b
    const int br  = blk >> 3;
    const int b   = blk & 7;
    const int t   = threadIdx.x;

    __shared__ float fr[CC * MODES], fi[CC * MODES];
    __shared__ float bxr[OO * MODES], bxi[OO * MODES];
    __shared__ float twc[15][256], tws[15][256];

    // Phase 1: ft[c][k] = norm * sum_j pft[b*64+c][j][br][k]
    // row branch: rm already /W; ortho 1/sqrt(256) -> 1/16
    // col branch: cs raw sums over h -> 1/256, ortho -> 1/16
    const float norm = br ? (1.0f / (16.0f * 256.0f)) : (1.0f / 16.0f);
    #pragma unroll
    for (int q = 0; q < 4; ++q) {
        const int idx = t * 4 + q;           // 0..1023
        const int c = idx >> 4, k = idx & 15;
        float re = 0.f, im = 0.f;
        #pragma unroll
        for (int jj = 0; jj < 4; ++jj) {
            const float* p = pft + ((((size_t)(b * 64 + c) * 4 + jj) * 2 + br) * 16 + k) * 2;
            re += p[0]; im += p[1];
        }
        fr[c * MODES + k] = re * norm;
        fi[c * MODES + k] = im * norm;
    }
    __syncthreads();

    // Phase 2: modemix  box[o][k] = sum_c ft[c][k] * w[c,o,k]
    const float* wr = br ? wyr : wxr;
    const float* wi = br ? wyi : wxi;
    const int k2 = t & 15;
    const int ob = t >> 4;
    #pragma unroll
    for (int p = 0; p < 4; ++p) {
        const int o = ob + p * 16;
        float are = 0.f, aim = 0.f;
        for (int c = 0; c < CC; ++c) {
            const float frv = fr[c * MODES + k2];
            const float fiv = fi[c * MODES + k2];
            const float wrv = wr[(c * OO + o) * MODES + k2];
            const float wiv = wi[(c * OO + o) * MODES + k2];
            are += frv * wrv - fiv * wiv;
            aim += frv * wiv + fiv * wrv;
        }
        bxr[o * MODES + k2] = are;
        bxi[o * MODES + k2] = aim;
    }

    // Phase 3: twiddle table for synthesis (position = t)
    #pragma unroll
    for (int k = 1; k < MODES; ++k) {
        float s, c;
        sincosf(TWO_PI * (float)k * (float)t / 256.0f, &s, &c);
        twc[k - 1][t] = c;
        tws[k - 1][t] = s;
    }
    __syncthreads();

    // Phase 4: synth. thread t = position; loop over o.
    for (int o = 0; o < OO; ++o) {
        float acc = bxr[o * MODES];
        #pragma unroll
        for (int k = 1; k < MODES; ++k)
            acc += 2.0f * (bxr[o * MODES + k] * twc[k - 1][t] -
                           bxi[o * MODES + k] * tws[k - 1][t]);
        float v = acc * (1.0f / 16.0f);
        if (br == 0) v += mb[o];
        g[((size_t)blk * OO + o) * 256 + t] = v;
    }
}

// ---------------------------------------------------------------------------
// K3: MFMA epilogue GEMM, ot-merged, pure bf16 single-term. (unchanged r5)
// out[b,o,h,w] = sum_c mw[o,c] x[b,c,h,w] + gx'[b,o,h] + gy[b,o,w]
// grid = B*256 (one h-row per block); 4 waves; wave wv handles pixels
// [wv*64, wv*64+64) as two 32-px tiles, computing ALL 64 o per tile.
// Flat 32-load gather (round 4's per-kb scoping serialized: 149us vs 78us).
// No min-waves clamp (round 3: (256,4) -> 64 VGPR, spill).
__global__ void __launch_bounds__(256) k_final_mfma(
        const float* __restrict__ x,
        const float* __restrict__ mw,   // [O][C]
        const float* __restrict__ g,    // [2][B][O][256]
        float* __restrict__ out) {
    const int tid  = threadIdx.x;
    const int lane = tid & 63;
    const int wv   = tid >> 6;
    const int blk  = blockIdx.x;
    const int b    = blk >> 8;
    const int h    = blk & 255;
    const int nlo  = lane & 31;
    const int half = lane >> 5;

    const float* gx = g + (size_t)(b * OO) * 256;
    const float* gy = g + (size_t)BB * OO * 256 + (size_t)(b * OO) * 256;

    // gx[o,h] is block-uniform in h: hoist to LDS once.
    __shared__ float gxs[OO];
    if (tid < OO) gxs[tid] = gx[tid * 256 + h];

    // A fragments (weights) for both o-tiles, bf16, loaded once.
    short8v wf[2][4];
    #pragma unroll
    for (int ot = 0; ot < 2; ++ot) {
        const int o = ot * 32 + nlo;
        const float* wrow = mw + o * CC + 8 * half;
        #pragma unroll
        for (int kb = 0; kb < 4; ++kb) {
            int4v wi;
            #pragma unroll
            for (int p = 0; p < 4; ++p)
                wi[p] = (int)pack_bf16(wrow[kb * 16 + 2 * p], wrow[kb * 16 + 2 * p + 1]);
            wf[ot][kb] = __builtin_bit_cast(short8v, wi);
        }
    }
    __syncthreads();

    const float* xb = x + (size_t)b * CC * (HH * WW) + (size_t)h * WW;
    float*       ob = out + (size_t)b * OO * (HH * WW) + (size_t)h * WW;

    #pragma unroll
    for (int it = 0; it < 2; ++it) {
        const int w0 = wv * 64 + it * 32;

        // gather B: x[c][h][w0+nlo], c = kb*16 + 8*half + i — ALL 32 loads
        // issued flat before any use (32 in flight per lane).
        float xv[32];
        #pragma unroll
        for (int kb = 0; kb < 4; ++kb)
            #pragma unroll
            for (int i = 0; i < 8; ++i) {
                const int c = kb * 16 + 8 * half + i;
                xv[kb * 8 + i] = xb[(size_t)c * (HH * WW) + w0 + nlo];
            }

        short8v xh[4];
        #pragma unroll
        for (int kb = 0; kb < 4; ++kb) {
            int4v xi;
            #pragma unroll
            for (int p = 0; p < 4; ++p)
                xi[p] = (int)pack_bf16(xv[kb * 8 + 2 * p], xv[kb * 8 + 2 * p + 1]);
            xh[kb] = __builtin_bit_cast(short8v, xi);
        }

        f32x16 acc0, acc1;
        #pragma unroll
        for (int i = 0; i < 16; ++i) { acc0[i] = 0.f; acc1[i] = 0.f; }

        #pragma unroll
        for (int kb = 0; kb < 4; ++kb) {
            acc0 = __builtin_amdgcn_mfma_f32_32x32x16_bf16(wf[0][kb], xh[kb], acc0, 0, 0, 0);
            acc1 = __builtin_amdgcn_mfma_f32_32x32x16_bf16(wf[1][kb], xh[kb], acc1, 0, 0, 0);
        }

        // epilogue: row(o_local) = (r&3) + 8*(r>>2) + 4*half, col = nlo
        #pragma unroll
        for (int r = 0; r < 16; ++r) {
            const int ol = (r & 3) + 8 * (r >> 2) + 4 * half;
            {
                const int o = ol;
                const float v = acc0[r] + gxs[o] + gy[o * 256 + w0 + nlo];
                __builtin_nontemporal_store(v, &ob[(size_t)o * (HH * WW) + w0 + nlo]);
            }
            {
                const int o = 32 + ol;
                const float v = acc1[r] + gxs[o] + gy[o * 256 + w0 + nlo];
                __builtin_nontemporal_store(v, &ob[(size_t)o * (HH * WW) + w0 + nlo]);
            }
        }
    }
}

// ---------------------------------------------------------------------------
extern "C" void kernel_launch(void* const* d_in, const int* in_sizes, int n_in,
                              void* d_out, int out_size, void* d_ws, size_t ws_size,
                              hipStream_t stream) {
    const float* x    = (const float*)d_in[0];
    const float* wxr  = (const float*)d_in[1];
    const float* wxi  = (const float*)d_in[2];
    const float* wyr  = (const float*)d_in[3];
    const float* wyi  = (const float*)d_in[4];
    const float* mixw = (const float*)d_in[5];
    const float* mixb = (const float*)d_in[6];
    float* out = (float*)d_out;
    float* ws  = (float*)d_ws;

    float* pft = ws + WS_PFT;
    float* g   = ws + WS_G;

    k_means_dft<<<BB * CC * 4, 256, 0, stream>>>(x, pft);
    k_spectral<<<16, 256, 0, stream>>>(pft, wxr, wxi, wyr, wyi, mixb, g);
    k_final_mfma<<<BB * 256, 256, 0, stream>>>(x, mixw, g, out);
}

// Round 8
// 107.109 us; speedup vs baseline: 1.1658x; 1.1658x over previous
//
#include <hip/hip_runtime.h>
#include <hip/hip_bf16.h>
#include <cstddef>

// Problem constants
#define BB 8
#define CC 64
#define OO 64
#define HH 256
#define WW 256
#define MODES 16

// Workspace layout (float offsets)
#define WS_XBAR   0
#define WS_FTRE   262144
#define WS_FTIM   278528
#define WS_BOXRE  294912
#define WS_BOXIM  311296
#define WS_G      327680

typedef __attribute__((ext_vector_type(8)))  short short8v;
typedef __attribute__((ext_vector_type(16))) float f32x16;

// f32 -> bf16 bits via HIP builtin (RNE). NO inline asm: round 7 showed the
// hand-written v_cvt_pk_bf16_f32 asm miscompiles under a pipelined schedule
// (absmax 1.69); the compiler emits cvt_pk itself from scalar casts (m240).
__device__ __forceinline__ short f2bf_s(float v) {
    return (short)__builtin_bit_cast(unsigned short, __float2bfloat16(v));
}

// ---------------------------------------------------------------------------
// K1: grid = B*C*4. Block j of slice bc handles rows [j*64, j*64+64):
//  - row means -> xbw[bc][h] (final)
//  - column partial sums over its 64 rows -> partial[bc*4+j][w] (in d_out!)
__global__ void k_means(const float* __restrict__ x,
                        float* __restrict__ xbw,       // [B*C][256]
                        float* __restrict__ partial) { // [B*C*4][256] (d_out scratch)
    const int blk = blockIdx.x;                  // bc*4 + j
    const int bc  = blk >> 2;
    const int j   = blk & 3;
    const int t   = threadIdx.x;
    const int wave = t >> 6;
    const int lane = t & 63;
    const float* xs = x + (size_t)bc * (HH * WW);

    __shared__ float colsum[4][WW];

    float c0 = 0.f, c1 = 0.f, c2 = 0.f, c3 = 0.f;
    const int h0 = j * 64 + wave * 16;
    for (int r = 0; r < 16; ++r) {
        const int h = h0 + r;
        const float4 v = *reinterpret_cast<const float4*>(xs + (size_t)h * WW + lane * 4);
        c0 += v.x; c1 += v.y; c2 += v.z; c3 += v.w;
        float rs = (v.x + v.y) + (v.z + v.w);
        #pragma unroll
        for (int off = 32; off > 0; off >>= 1) rs += __shfl_xor(rs, off, 64);
        if (lane == 0) xbw[bc * HH + h] = rs * (1.0f / WW);
    }
    colsum[wave][lane * 4 + 0] = c0;
    colsum[wave][lane * 4 + 1] = c1;
    colsum[wave][lane * 4 + 2] = c2;
    colsum[wave][lane * 4 + 3] = c3;
    __syncthreads();
    partial[blk * WW + t] =
        (colsum[0][t] + colsum[1][t]) + (colsum[2][t] + colsum[3][t]);
}

// ---------------------------------------------------------------------------
// K2a: 16-mode ortho DFT. blk<512: row-mean vectors (xbw). blk>=512: column
// means assembled from the 4 partials (divide by H here).
__global__ void k_dft(const float* __restrict__ xbw,
                      const float* __restrict__ partial,
                      float* __restrict__ ftre,        // [1024][16]
                      float* __restrict__ ftim) {
    const int blk = blockIdx.x;
    const int t = threadIdx.x;
    __shared__ float vs[256];
    if (blk < 512) {
        vs[t] = xbw[(size_t)blk * 256 + t];
    } else {
        const int bc = blk - 512;
        vs[t] = ((partial[(bc * 4 + 0) * 256 + t] + partial[(bc * 4 + 1) * 256 + t]) +
                 (partial[(bc * 4 + 2) * 256 + t] + partial[(bc * 4 + 3) * 256 + t])) *
                (1.0f / HH);
    }
    __syncthreads();

    const int k = t >> 4;
    const int j = t & 15;
    float sre = 0.f, sim = 0.f;
    const float wk = 6.2831853071795864769f * (float)k / 256.0f;
    #pragma unroll
    for (int i = 0; i < 16; ++i) {
        const int h = j * 16 + i;
        float s, c;
        sincosf(wk * (float)h, &s, &c);
        sre += vs[h] * c;
        sim -= vs[h] * s;
    }
    #pragma unroll
    for (int m = 1; m < 16; m <<= 1) {
        sre += __shfl_xor(sre, m, 64);
        sim += __shfl_xor(sim, m, 64);
    }
    if (j == 0) {
        ftre[blk * MODES + k] = sre * (1.0f / 16.0f);
        ftim[blk * MODES + k] = sim * (1.0f / 16.0f);
    }
}

// ---------------------------------------------------------------------------
// K2b: channel mix in mode space.
__global__ void k_modemix(const float* __restrict__ ftre,
                          const float* __restrict__ ftim,
                          const float* __restrict__ wxr, const float* __restrict__ wxi,
                          const float* __restrict__ wyr, const float* __restrict__ wyi,
                          float* __restrict__ boxre, float* __restrict__ boxim) {
    const int blk = blockIdx.x;      // 0..15 : br = blk>>3, b = blk&7
    const int br  = blk >> 3;
    const int t   = threadIdx.x;

    const float* wr = br ? wyr : wxr;
    const float* wi = br ? wyi : wxi;

    __shared__ float fr[CC * MODES];
    __shared__ float fi[CC * MODES];
    #pragma unroll
    for (int i = 0; i < 4; ++i) {
        fr[t + i * 256] = ftre[blk * (CC * MODES) + t + i * 256];
        fi[t + i * 256] = ftim[blk * (CC * MODES) + t + i * 256];
    }
    __syncthreads();

    const int k  = t & 15;
    const int ob = t >> 4;
    #pragma unroll
    for (int p = 0; p < 4; ++p) {
        const int o = ob + p * 16;
        float are = 0.f, aim = 0.f;
        for (int c = 0; c < CC; ++c) {
            const float frv = fr[c * MODES + k];
            const float fiv = fi[c * MODES + k];
            const float wrv = wr[(c * OO + o) * MODES + k];
            const float wiv = wi[(c * OO + o) * MODES + k];
            are += frv * wrv - fiv * wiv;
            aim += frv * wiv + fiv * wrv;
        }
        boxre[blk * (OO * MODES) + o * MODES + k] = are;
        boxim[blk * (OO * MODES) + o * MODES + k] = aim;
    }
}

// ---------------------------------------------------------------------------
// K2c: inverse synthesis; mix_b folded into gx (br==0).
__global__ void k_synth(const float* __restrict__ boxre,
                        const float* __restrict__ boxim,
                        const float* __restrict__ mb,
                        float* __restrict__ g) {
    const int blk = blockIdx.x;      // (br*B+b)*64 + o
    const int t   = threadIdx.x;
    __shared__ float bre[MODES], bim[MODES];
    if (t < MODES)        bre[t] = boxre[(blk >> 6) * (OO * MODES) + (blk & 63) * MODES + t];
    else if (t < 2*MODES) bim[t - MODES] = boxim[(blk >> 6) * (OO * MODES) + (blk & 63) * MODES + (t - MODES)];
    __syncthreads();

    float acc = bre[0];
    const float wt = 6.2831853071795864769f * (float)t / 256.0f;
    #pragma unroll
    for (int k = 1; k < MODES; ++k) {
        float s, c;
        sincosf(wt * (float)k, &s, &c);
        acc += 2.0f * (bre[k] * c - bim[k] * s);
    }
    float v = acc * (1.0f / 16.0f);
    if (blk < BB * OO) v += mb[blk & 63];
    g[(size_t)blk * 256 + t] = v;
}

// ---------------------------------------------------------------------------
// K3: MFMA epilogue GEMM, ot-merged, pure bf16, pipelined, NO inline asm.
// out[b,o,h,w] = sum_c mw[o,c] x[b,c,h,w] + gx'[b,o,h] + gy[b,o,w]
// grid = B*256 (one h-row per block); 4 waves; wave wv covers pixels
// [wv*64, wv*64+64) as two 32-px tiles; ALL 64 o per tile from one x load.
// Schedule per wave: gather(tile0) -> cvt0 -> RE-ISSUE gather into xv for
// tile1 (WAR on xv regs; latency hides under tile-0 mfma+epilogues) ->
// mfma+epi ot0 -> mfma+epi ot1 -> cvt1 -> mfma+epi ot0 -> mfma+epi ot1.
// Single f32x16 acc reused (keeps peak VGPR ~104, inside the 65-128 band).
// Flat 32-load gathers (round 4's per-kb scoping serialized: 149us vs 78us).
// No min-waves clamp (round 3: (256,4) -> 64 VGPR, spill).
__global__ void __launch_bounds__(256) k_final_mfma(
        const float* __restrict__ x,
        const float* __restrict__ mw,   // [O][C]
        const float* __restrict__ g,    // [2][B][O][256]
        float* __restrict__ out) {
    const int tid  = threadIdx.x;
    const int lane = tid & 63;
    const int wv   = tid >> 6;
    const int blk  = blockIdx.x;
    const int b    = blk >> 8;
    const int h    = blk & 255;
    const int nlo  = lane & 31;
    const int half = lane >> 5;

    const float* gx = g + (size_t)(b * OO) * 256;
    const float* gy = g + (size_t)BB * OO * 256 + (size_t)(b * OO) * 256;

    // gx[o,h] is block-uniform in h: hoist to LDS once.
    __shared__ float gxs[OO];
    if (tid < OO) gxs[tid] = gx[tid * 256 + h];

    // A fragments (weights) for both o-tiles, bf16, loaded once.
    short8v wf[2][4];
    #pragma unroll
    for (int ot = 0; ot < 2; ++ot) {
        const int o = ot * 32 + nlo;
        const float* wrow = mw + o * CC + 8 * half;
        #pragma unroll
        for (int kb = 0; kb < 4; ++kb) {
            short8v wi;
            #pragma unroll
            for (int i = 0; i < 8; ++i)
                wi[i] = f2bf_s(wrow[kb * 16 + i]);
            wf[ot][kb] = wi;
        }
    }
    __syncthreads();

    const float* xb = x + (size_t)b * CC * (HH * WW) + (size_t)h * WW;
    float*       ob = out + (size_t)b * OO * (HH * WW) + (size_t)h * WW;

    const int w0a = wv * 64;
    const int w0b = wv * 64 + 32;

    // ---- tile 0 gather: flat 32 loads ----
    float xv[32];
    #pragma unroll
    for (int kb = 0; kb < 4; ++kb)
        #pragma unroll
        for (int i = 0; i < 8; ++i) {
            const int c = kb * 16 + 8 * half + i;
            xv[kb * 8 + i] = xb[(size_t)c * (HH * WW) + w0a + nlo];
        }

    // cvt tile 0 (waits on tile-0 loads; xv regs then free for reuse)
    short8v xh[4];
    #pragma unroll
    for (int kb = 0; kb < 4; ++kb) {
        short8v xi;
        #pragma unroll
        for (int i = 0; i < 8; ++i) xi[i] = f2bf_s(xv[kb * 8 + i]);
        xh[kb] = xi;
    }

    // ---- tile 1 gather: issue NOW into xv (WAR), flies under tile-0 work ----
    #pragma unroll
    for (int kb = 0; kb < 4; ++kb)
        #pragma unroll
        for (int i = 0; i < 8; ++i) {
            const int c = kb * 16 + 8 * half + i;
            xv[kb * 8 + i] = xb[(size_t)c * (HH * WW) + w0b + nlo];
        }

    f32x16 acc;

    // ---- tile 0, o-tile 0 ----
    #pragma unroll
    for (int i = 0; i < 16; ++i) acc[i] = 0.f;
    #pragma unroll
    for (int kb = 0; kb < 4; ++kb)
        acc = __builtin_amdgcn_mfma_f32_32x32x16_bf16(wf[0][kb], xh[kb], acc, 0, 0, 0);
    #pragma unroll
    for (int r = 0; r < 16; ++r) {
        const int o = (r & 3) + 8 * (r >> 2) + 4 * half;
        const float v = acc[r] + gxs[o] + gy[o * 256 + w0a + nlo];
        __builtin_nontemporal_store(v, &ob[(size_t)o * (HH * WW) + w0a + nlo]);
    }

    // ---- tile 0, o-tile 1 ----
    #pragma unroll
    for (int i = 0; i < 16; ++i) acc[i] = 0.f;
    #pragma unroll
    for (int kb = 0; kb < 4; ++kb)
        acc = __builtin_amdgcn_mfma_f32_32x32x16_bf16(wf[1][kb], xh[kb], acc, 0, 0, 0);
    #pragma unroll
    for (int r = 0; r < 16; ++r) {
        const int o = 32 + (r & 3) + 8 * (r >> 2) + 4 * half;
        const float v = acc[r] + gxs[o] + gy[o * 256 + w0a + nlo];
        __builtin_nontemporal_store(v, &ob[(size_t)o * (HH * WW) + w0a + nlo]);
    }

    // ---- tile 1: cvt (loads have landed), then both o-tiles ----
    #pragma unroll
    for (int kb = 0; kb < 4; ++kb) {
        short8v xi;
        #pragma unroll
        for (int i = 0; i < 8; ++i) xi[i] = f2bf_s(xv[kb * 8 + i]);
        xh[kb] = xi;
    }

    #pragma unroll
    for (int i = 0; i < 16; ++i) acc[i] = 0.f;
    #pragma unroll
    for (int kb = 0; kb < 4; ++kb)
        acc = __builtin_amdgcn_mfma_f32_32x32x16_bf16(wf[0][kb], xh[kb], acc, 0, 0, 0);
    #pragma unroll
    for (int r = 0; r < 16; ++r) {
        const int o = (r & 3) + 8 * (r >> 2) + 4 * half;
        const float v = acc[r] + gxs[o] + gy[o * 256 + w0b + nlo];
        __builtin_nontemporal_store(v, &ob[(size_t)o * (HH * WW) + w0b + nlo]);
    }

    #pragma unroll
    for (int i = 0; i < 16; ++i) acc[i] = 0.f;
    #pragma unroll
    for (int kb = 0; kb < 4; ++kb)
        acc = __builtin_amdgcn_mfma_f32_32x32x16_bf16(wf[1][kb], xh[kb], acc, 0, 0, 0);
    #pragma unroll
    for (int r = 0; r < 16; ++r) {
        const int o = 32 + (r & 3) + 8 * (r >> 2) + 4 * half;
        const float v = acc[r] + gxs[o] + gy[o * 256 + w0b + nlo];
        __builtin_nontemporal_store(v, &ob[(size_t)o * (HH * WW) + w0b + nlo]);
    }
}

// ---------------------------------------------------------------------------
extern "C" void kernel_launch(void* const* d_in, const int* in_sizes, int n_in,
                              void* d_out, int out_size, void* d_ws, size_t ws_size,
                              hipStream_t stream) {
    const float* x    = (const float*)d_in[0];
    const float* wxr  = (const float*)d_in[1];
    const float* wxi  = (const float*)d_in[2];
    const float* wyr  = (const float*)d_in[3];
    const float* wyi  = (const float*)d_in[4];
    const float* mixw = (const float*)d_in[5];
    const float* mixb = (const float*)d_in[6];
    float* out = (float*)d_out;
    float* ws  = (float*)d_ws;

    float* xbw   = ws + WS_XBAR;
    float* ftre  = ws + WS_FTRE;
    float* ftim  = ws + WS_FTIM;
    float* boxre = ws + WS_BOXRE;
    float* boxim = ws + WS_BOXIM;
    float* g     = ws + WS_G;
    float* partial = out;    // d_out as scratch: dead until k_final overwrites

    k_means<<<BB * CC * 4, 256, 0, stream>>>(x, xbw, partial);
    k_dft<<<2 * BB * CC, 256, 0, stream>>>(xbw, partial, ftre, ftim);
    k_modemix<<<2 * BB, 256, 0, stream>>>(ftre, ftim, wxr, wxi, wyr, wyi, boxre, boxim);
    k_synth<<<2 * BB * OO, 256, 0, stream>>>(boxre, boxim, mixb, g);
    k_final_mfma<<<BB * 256, 256, 0, stream>>>(x, mixw, g, out);
}